// Round 10
// baseline (192.517 us; speedup 1.0000x reference)
//
#include <hip/hip_runtime.h>

#define B_ 32
#define C_ 64
#define N_ 1024
#define T_ 64

typedef __attribute__((ext_vector_type(8))) _Float16 half8;   // 8 f16 = 4 VGPR
typedef __attribute__((ext_vector_type(4))) _Float16 half4;
typedef __attribute__((ext_vector_type(4))) float f32x4;

// ---------------------------------------------------------------------------
// R24: R23's fusion with R16's PROVEN flag-sync (cooperative launch failed
// silently at grid==co-residency bound -> out stayed zeroed). One kernel,
// 512 blocks x 512 thr (2/CU; capacity 4/CU at 35KB LDS & <=128 VGPR -> all
// resident, spin-safe; R16 precedent). Each block produces the SAME 64 rows
// it later consumes as A-rows:
//   Phase 1: NT x-stream -> q -> q_h global + qsh LDS; split-precision qw
//            MFMA -> qwh LDS (hides under read stream). ALL blocks produce.
//   Sync:    per-batch flag (16 producers); batch b's 16 blocks share one XCD
//            slot (bid&7 = b>>2) -> XCD-local spin + L2-local q_h traffic.
//   Phase 2: R21's store-streaming tile loop (zero global loads inside, LDS-
//            only barriers, red[2] dbuf) -- K2's serial head is gone.
// Math bit-identical to R21 -> absmax 0.00390625. Predict 107-112us.
// ---------------------------------------------------------------------------

__global__ void k_init(int* flags) {
    if (threadIdx.x < 32) flags[threadIdx.x] = 0;
}

__global__ __launch_bounds__(512, 4) void k_fused(
        const float* __restrict__ x,
        const float* __restrict__ W,
        const float* __restrict__ alpha,
        float* __restrict__ out,
        _Float16* __restrict__ q_h,
        int* __restrict__ flags) {
    const int bid = blockIdx.x;
    const int s   = (bid & 7) * 64 + (bid >> 3);    // bijective, 512%8==0
    const int b   = s >> 4;                         // batch (XCD-aligned)
    const int n0  = (s & 15) * 64;                  // 64-row tile base
    const int tid  = threadIdx.x;
    const int w    = tid >> 6;                      // wave 0..7
    const int lane = tid & 63;
    const int lr   = lane & 15;
    const int lk   = lane >> 4;

    __shared__ float Ws[T_][T_];                    // 16 KB fp32 W
    __shared__ _Float16 qsh[64][72];                // 9 KB f16 q rows (own 64)
    __shared__ _Float16 qwh[64][72];                // 9 KB f16 qw tile
    __shared__ float red[2][16][8];                 // 1 KB, double-buffered

    // ================= PHASE 1: q-reduction + qw prologue ==================
    // ---- stage W (fp32, coalesced; 2 chunks/thread) ----
    {
        const f32x4* Wv = (const f32x4*)W;
        f32x4* Wd = (f32x4*)&Ws[0][0];
        Wd[tid]       = Wv[tid];
        Wd[tid + 512] = Wv[tid + 512];
    }

    // ---- q = sum_c alpha[c]*x for rows n0..n0+63 (NT read-once stream) ----
    // chunk tid -> row r0 = tid>>4, cols (tid&15)*4; chunk tid+512 -> r0+32.
    {
        const f32x4* xb = (const f32x4*)(x + (size_t)b * C_ * N_ * T_
                                           + (size_t)n0 * T_);
        f32x4 acc0 = {0.f, 0.f, 0.f, 0.f};
        f32x4 acc1 = {0.f, 0.f, 0.f, 0.f};
#pragma unroll 4
        for (int c = 0; c < C_; ++c) {
            const f32x4* xc = xb + (size_t)c * (N_ * T_ / 4);
            f32x4 v0 = __builtin_nontemporal_load(xc + tid);
            f32x4 v1 = __builtin_nontemporal_load(xc + tid + 512);
            const float ac = alpha[c];
            acc0[0] += ac * v0[0]; acc0[1] += ac * v0[1];
            acc0[2] += ac * v0[2]; acc0[3] += ac * v0[3];
            acc1[0] += ac * v1[0]; acc1[1] += ac * v1[1];
            acc1[2] += ac * v1[2]; acc1[3] += ac * v1[3];
        }
        const int r0 = tid >> 4;
        const int c4 = (tid & 15) * 4;
        half4 h0, h1;
#pragma unroll
        for (int j = 0; j < 4; ++j) { h0[j] = (_Float16)acc0[j];
                                      h1[j] = (_Float16)acc1[j]; }   // RTNE
        *(half4*)(q_h + ((size_t)b * N_ + n0 + r0) * T_ + c4)      = h0;
        *(half4*)(q_h + ((size_t)b * N_ + n0 + r0 + 32) * T_ + c4) = h1;
        *(half4*)&qsh[r0][c4]      = h0;
        *(half4*)&qsh[r0 + 32][c4] = h1;
    }
    __syncthreads();                                // q_h stores drained (vmcnt0)

    // ---- qw (64x64) = q @ W via MFMA, split-precision W (hi+lo f16) ----
    // wave w: col-block tc = w&3; row-blocks tr0, tr0+1.
    {
        const int tc  = w & 3;
        const int tr0 = (w >> 2) * 2;
        half8 bh0, bh1, bl0, bl1;
#pragma unroll
        for (int j = 0; j < 8; ++j) {
            const float wv0 = Ws[lk * 8 + j][tc * 16 + lr];
            const float wv1 = Ws[lk * 8 + 32 + j][tc * 16 + lr];
            const _Float16 h0 = (_Float16)wv0;
            const _Float16 h1 = (_Float16)wv1;
            bh0[j] = h0; bl0[j] = (_Float16)(wv0 - (float)h0);
            bh1[j] = h1; bl1[j] = (_Float16)(wv1 - (float)h1);
        }
#pragma unroll
        for (int i = 0; i < 2; ++i) {
            const int tr = tr0 + i;
            half8 a0 = *(const half8*)&qsh[tr * 16 + lr][lk * 8];
            half8 a1 = *(const half8*)&qsh[tr * 16 + lr][lk * 8 + 32];
            f32x4 a = {0.f, 0.f, 0.f, 0.f};
            a = __builtin_amdgcn_mfma_f32_16x16x32_f16(a0, bh0, a, 0, 0, 0);
            a = __builtin_amdgcn_mfma_f32_16x16x32_f16(a1, bh1, a, 0, 0, 0);
            a = __builtin_amdgcn_mfma_f32_16x16x32_f16(a0, bl0, a, 0, 0, 0);
            a = __builtin_amdgcn_mfma_f32_16x16x32_f16(a1, bl1, a, 0, 0, 0);
            // C layout: col = lr, row = lk*4 + r
#pragma unroll
            for (int r = 0; r < 4; ++r)
                qwh[tr * 16 + lk * 4 + r][tc * 16 + lr] = (_Float16)a[r];
        }
    }

    // ================= SYNC: per-batch flag (R16-proven pattern) ===========
    if (tid == 0) {
        __threadfence();                            // q_h visible device-wide
        __hip_atomic_fetch_add(&flags[b], 1,
                               __ATOMIC_RELEASE, __HIP_MEMORY_SCOPE_AGENT);
        while (__hip_atomic_load(&flags[b], __ATOMIC_RELAXED,
                                 __HIP_MEMORY_SCOPE_AGENT) < 16)
            __builtin_amdgcn_s_sleep(2);
        __threadfence();                            // acquire: fresh q_h reads
    }
    __syncthreads();                                // broadcast; qwh ready too

    // ================= PHASE 2: R21 store-streaming tile loop ==============
    // ---- load ALL 16 B-stripe frags ONCE (tile-independent) ----
    half8 bst0[8], bst1[8];                         // 64 VGPR, live whole loop
    {
        const size_t cb0 = ((size_t)b * N_ + w * 128 + lr) * T_ + lk * 8;
#pragma unroll
        for (int cf = 0; cf < 8; ++cf) {
            bst0[cf] = *(const half8*)(q_h + cb0 + (size_t)cf * 16 * T_);
            bst1[cf] = *(const half8*)(q_h + cb0 + (size_t)cf * 16 * T_ + 32);
        }
    }

    float* const obase = out + ((size_t)b * N_ + n0 + lr) * N_ + w * 128 + lk * 4;

    // ---- 4 row-tiles; tile g's stores drain under tile g+1's compute ----
#pragma unroll 1
    for (int g = 0; g < 4; ++g) {
        half8 af0 = *(const half8*)&qwh[g * 16 + lr][lk * 8];
        half8 af1 = *(const half8*)&qwh[g * 16 + lr][lk * 8 + 32];

        f32x4 acc[8];
#pragma unroll
        for (int cf = 0; cf < 8; ++cf) {
            // swapped operands: lane owns out row n0+g*16+lr,
            // reg r = col w*128+cf*16+lk*4+r (4 consecutive floats)
            f32x4 a = {0.f, 0.f, 0.f, 0.f};
            a = __builtin_amdgcn_mfma_f32_16x16x32_f16(bst0[cf], af0, a, 0, 0, 0);
            a = __builtin_amdgcn_mfma_f32_16x16x32_f16(bst1[cf], af1, a, 0, 0, 0);
            acc[cf] = a;
        }

        // ---- max-free softmax for these 16 rows ----
        float ssum = 0.f;
#pragma unroll
        for (int cf = 0; cf < 8; ++cf) {
#pragma unroll
            for (int r = 0; r < 4; ++r) {
                float e = __expf(acc[cf][r]);
                acc[cf][r] = e;
                ssum += e;
            }
        }
        ssum += __shfl_xor(ssum, 16);               // sum across lk group
        ssum += __shfl_xor(ssum, 32);
        if (lane < 16) red[g & 1][lr][w] = ssum;

        // LDS-ONLY barrier: lgkmcnt drained, vmcnt NOT -> prior tile's global
        // stores keep draining under this barrier and the next tile's compute.
        asm volatile("s_waitcnt lgkmcnt(0)" ::: "memory");
        __builtin_amdgcn_s_barrier();
        asm volatile("" ::: "memory");

        f32x4 p0 = *(f32x4*)&red[g & 1][lr][0];
        f32x4 p1 = *(f32x4*)&red[g & 1][lr][4];
        const float inv = 1.0f / (p0[0] + p0[1] + p0[2] + p0[3] +
                                  p1[0] + p1[1] + p1[2] + p1[3]);
        f32x4* orow = (f32x4*)(obase + (size_t)g * 16 * N_);
#pragma unroll
        for (int cf = 0; cf < 8; ++cf) {
            f32x4 v = acc[cf];
            v[0] *= inv; v[1] *= inv; v[2] *= inv; v[3] *= inv;
            orow[cf * 4] = v;                       // dwordx4; no vmcnt consumer
        }
    }
}

// ---------------------------------------------------------------------------
extern "C" void kernel_launch(void* const* d_in, const int* in_sizes, int n_in,
                              void* d_out, int out_size, void* d_ws, size_t ws_size,
                              hipStream_t stream) {
    const float* x     = (const float*)d_in[0];
    const float* W     = (const float*)d_in[1];
    const float* alpha = (const float*)d_in[2];
    float* out = (float*)d_out;

    _Float16* q_h = (_Float16*)d_ws;                         // [B,N,T] f16, 4 MB
    int* flags    = (int*)((char*)d_ws + (4u << 20));        // 32 ints

    k_init<<<1, 32, 0, stream>>>(flags);
    k_fused<<<512, 512, 0, stream>>>(x, W, alpha, out, q_h, flags);
}

// Round 11
// 116.785 us; speedup vs baseline: 1.6485x; 1.6485x over previous
//
#include <hip/hip_runtime.h>

#define B_ 32
#define C_ 64
#define N_ 1024
#define T_ 64

typedef __attribute__((ext_vector_type(8))) _Float16 half8;   // 8 f16 = 4 VGPR
typedef __attribute__((ext_vector_type(4))) _Float16 half4;
typedef __attribute__((ext_vector_type(4))) float f32x4;

// ---------------------------------------------------------------------------
// K1: q = sum_c alpha[c]*x[b,c,:,:], stored as ONE fp16 plane. Pure stream,
// NT loads on x (read-once), ~93-95% read ceiling. At floor — do not touch.
// (Fusion verdict after R16/R23/R24: moving ANY work across the producer/
// consumer boundary into one kernel loses 60-160us. Two-kernel split stays.)
// ---------------------------------------------------------------------------
__global__ __launch_bounds__(256) void k_q(const float* __restrict__ x,
                                           const float* __restrict__ alpha,
                                           _Float16* __restrict__ q_h) {
    const int bid = blockIdx.x;
    const int s1  = (bid & 7) * 256 + (bid >> 3);   // bijective, 2048%8==0
    const int b   = s1 >> 6;
    const int n0  = (s1 & 63) * 16;
    const int tid = threadIdx.x;

    const f32x4* xb = (const f32x4*)(x + (size_t)b * C_ * N_ * T_
                                       + (size_t)n0 * T_);
    f32x4 acc = {0.f, 0.f, 0.f, 0.f};
#pragma unroll 4
    for (int c = 0; c < C_; ++c) {
        f32x4 v = __builtin_nontemporal_load(&xb[(size_t)c * (N_ * T_ / 4) + tid]);
        const float ac = alpha[c];
        acc[0] += ac * v[0]; acc[1] += ac * v[1];
        acc[2] += ac * v[2]; acc[3] += ac * v[3];
    }

    half4 h;
#pragma unroll
    for (int j = 0; j < 4; ++j) h[j] = (_Float16)acc[j];   // RTNE cvt
    *(half4*)(q_h + ((size_t)b * N_ + n0) * T_ + (size_t)tid * 4) = h;
}

// ---------------------------------------------------------------------------
// K2 (R25): R21 body with the serial HEAD collapsed. R21's K2 = 17.2us drain
// (write ceiling) + ~12us latency-serial head at 2 blocks/CU. Changes:
//  1. bst loads hoisted to instruction 0 (depend on nothing; latency hides
//     under the rest of the head).
//  2. W LDS round-trip DELETED: each lane reads its 16 W f32s directly from
//     global (W is L2/L3-hot; 64B segments). Removes the stage, one barrier,
//     and the LDS write+read from the critical path. Same bits -> qw
//     bit-identical.
//  3. Head = {36 global loads all in flight} -> cvt/MFMA -> qwh -> ONE
//     barrier -> tile loop (byte-identical to R21: zero global loads inside,
//     LDS-only barriers, red[2] dbuf, stores drain under next tile).
// Predict K2 ~23-25, total ~111-114. Neutral -> head is fill/launch-bound ->
// R21 is the structural floor (assess ROOFLINE vs ~102-105 component bound).
// ---------------------------------------------------------------------------
__global__ __launch_bounds__(512, 4) void k_scores_softmax(
        const _Float16* __restrict__ q_h,
        const float* __restrict__ W,
        float* __restrict__ out) {
    const int bid = blockIdx.x;
    const int s   = (bid & 7) * 64 + (bid >> 3);    // bijective, 512%8==0
    const int b   = s >> 4;                         // same b<->XCD map as K1
    const int n0  = (s & 15) * 64;                  // 64-row tile base
    const int tid  = threadIdx.x;
    const int w    = tid >> 6;                      // wave 0..7 -> cols w*128
    const int lane = tid & 63;
    const int lr   = lane & 15;
    const int lk   = lane >> 4;

    __shared__ _Float16 qwh[64][72];                // 9 KB f16 qw tile
    __shared__ float red[2][16][8];                 // 1 KB, double-buffered

    // ---- 1) bst loads FIRST: 16 tile-independent frags, longest latency ----
    half8 bst0[8], bst1[8];                         // 64 VGPR, live whole loop
    const size_t cb0 = ((size_t)b * N_ + w * 128 + lr) * T_ + lk * 8;
#pragma unroll
    for (int cf = 0; cf < 8; ++cf) {
        bst0[cf] = *(const half8*)(q_h + cb0 + (size_t)cf * 16 * T_);
        bst1[cf] = *(const half8*)(q_h + cb0 + (size_t)cf * 16 * T_ + 32);
    }

    // ---- 2) W direct per-lane (no LDS round-trip; L2/L3-hot) ----
    // lane needs col tc*16+lr, rows lk*8+j and lk*8+32+j  (j=0..7)
    const int tc  = w & 3;
    const int tr0 = (w >> 2) * 2;
    float wv0[8], wv1[8];
#pragma unroll
    for (int j = 0; j < 8; ++j) {
        wv0[j] = W[(lk * 8 + j) * T_ + tc * 16 + lr];
        wv1[j] = W[(lk * 8 + 32 + j) * T_ + tc * 16 + lr];
    }
    half8 bh0, bh1, bl0, bl1;
#pragma unroll
    for (int j = 0; j < 8; ++j) {
        const _Float16 h0 = (_Float16)wv0[j];
        const _Float16 h1 = (_Float16)wv1[j];
        bh0[j] = h0; bl0[j] = (_Float16)(wv0[j] - (float)h0);
        bh1[j] = h1; bl1[j] = (_Float16)(wv1[j] - (float)h1);
    }

    // ---- 3) qw (2 row-blocks) = q @ W, split-precision, -> qwh LDS ----
#pragma unroll
    for (int i = 0; i < 2; ++i) {
        const int tr = tr0 + i;
        const size_t ar = ((size_t)b * N_ + n0 + tr * 16 + lr) * T_ + lk * 8;
        half8 a0 = *(const half8*)(q_h + ar);        // k = lk*8 .. +7
        half8 a1 = *(const half8*)(q_h + ar + 32);
        f32x4 a = {0.f, 0.f, 0.f, 0.f};
        a = __builtin_amdgcn_mfma_f32_16x16x32_f16(a0, bh0, a, 0, 0, 0);
        a = __builtin_amdgcn_mfma_f32_16x16x32_f16(a1, bh1, a, 0, 0, 0);
        a = __builtin_amdgcn_mfma_f32_16x16x32_f16(a0, bl0, a, 0, 0, 0);
        a = __builtin_amdgcn_mfma_f32_16x16x32_f16(a1, bl1, a, 0, 0, 0);
        // C layout: col = lr, row = lk*4 + r
#pragma unroll
        for (int r = 0; r < 4; ++r)
            qwh[tr * 16 + lk * 4 + r][tc * 16 + lr] = (_Float16)a[r];
    }
    __syncthreads();                                // ONE head barrier

    float* const obase = out + ((size_t)b * N_ + n0 + lr) * N_ + w * 128 + lk * 4;

    // ---- 4 row-tiles; tile g's stores drain under tile g+1's compute ----
#pragma unroll 1
    for (int g = 0; g < 4; ++g) {
        half8 af0 = *(const half8*)&qwh[g * 16 + lr][lk * 8];
        half8 af1 = *(const half8*)&qwh[g * 16 + lr][lk * 8 + 32];

        f32x4 acc[8];
#pragma unroll
        for (int cf = 0; cf < 8; ++cf) {
            // swapped operands: lane owns out row n0+g*16+lr,
            // reg r = col w*128+cf*16+lk*4+r (4 consecutive floats)
            f32x4 a = {0.f, 0.f, 0.f, 0.f};
            a = __builtin_amdgcn_mfma_f32_16x16x32_f16(bst0[cf], af0, a, 0, 0, 0);
            a = __builtin_amdgcn_mfma_f32_16x16x32_f16(bst1[cf], af1, a, 0, 0, 0);
            acc[cf] = a;
        }

        // ---- max-free softmax for these 16 rows ----
        float ssum = 0.f;
#pragma unroll
        for (int cf = 0; cf < 8; ++cf) {
#pragma unroll
            for (int r = 0; r < 4; ++r) {
                float e = __expf(acc[cf][r]);
                acc[cf][r] = e;
                ssum += e;
            }
        }
        ssum += __shfl_xor(ssum, 16);               // sum across lk group
        ssum += __shfl_xor(ssum, 32);
        if (lane < 16) red[g & 1][lr][w] = ssum;

        // LDS-ONLY barrier: lgkmcnt drained, vmcnt NOT -> prior tile's global
        // stores keep draining under this barrier and the next tile's compute.
        asm volatile("s_waitcnt lgkmcnt(0)" ::: "memory");
        __builtin_amdgcn_s_barrier();
        asm volatile("" ::: "memory");

        f32x4 p0 = *(f32x4*)&red[g & 1][lr][0];
        f32x4 p1 = *(f32x4*)&red[g & 1][lr][4];
        const float inv = 1.0f / (p0[0] + p0[1] + p0[2] + p0[3] +
                                  p1[0] + p1[1] + p1[2] + p1[3]);
        f32x4* orow = (f32x4*)(obase + (size_t)g * 16 * N_);
#pragma unroll
        for (int cf = 0; cf < 8; ++cf) {
            f32x4 v = acc[cf];
            v[0] *= inv; v[1] *= inv; v[2] *= inv; v[3] *= inv;
            orow[cf * 4] = v;                       // dwordx4; no vmcnt consumer
        }
    }
}

// ---------------------------------------------------------------------------
extern "C" void kernel_launch(void* const* d_in, const int* in_sizes, int n_in,
                              void* d_out, int out_size, void* d_ws, size_t ws_size,
                              hipStream_t stream) {
    const float* x     = (const float*)d_in[0];
    const float* W     = (const float*)d_in[1];
    const float* alpha = (const float*)d_in[2];
    float* out = (float*)d_out;

    _Float16* q_h = (_Float16*)d_ws;                // [B,N,T] f16, 4 MB

    k_q<<<2048, 256, 0, stream>>>(x, alpha, q_h);
    k_scores_softmax<<<512, 512, 0, stream>>>(q_h, W, out);
}